// Round 9
// baseline (585.180 us; speedup 1.0000x reference)
//
#include <hip/hip_runtime.h>

typedef _Float16 half8  __attribute__((ext_vector_type(8)));
typedef _Float16 half4  __attribute__((ext_vector_type(4)));
typedef float    float4v __attribute__((ext_vector_type(4)));
typedef float    float8v __attribute__((ext_vector_type(8)));

#define N_ROWS  65536   // 64*32*32
#define N_CODES 1024
#define DIM     256
#define BM      64      // rows per block (screen / fallback)
#define BM2     16      // rows per block (backstop exact)
#define NBLKS   (N_ROWS / BM)   // 1024

// ---- prep: one wave per code. ||e||^2 and hi/lo f16 split written in MFMA
// B-fragment order (16x16x32): frag block b = nt*8 + ks holds 1024 halves:
// [hi 512][lo 512], chunk p = quad*16 + l15 -> code = nt*16+l15,
// k = ks*32 + quad*8 + j.  Also resets the backstop counter.
__global__ __launch_bounds__(64)
void vq_prep(const float* __restrict__ emb, float* __restrict__ e_norm,
             _Float16* __restrict__ e_frag, int* __restrict__ count) {
    const int c = blockIdx.x, lane = threadIdx.x;
    const int l15 = c & 15, nt = c >> 4;
    if (count && c == 0 && lane == 0) *count = 0;
    float4v v = ((const float4v*)(emb + (size_t)c * DIM))[lane];
    half4 h, l;
    float ss = 0.f;
    #pragma unroll
    for (int j = 0; j < 4; ++j) {
        float x = v[j];
        ss += x * x;
        _Float16 hh = (_Float16)x;
        h[j] = hh;
        l[j] = (_Float16)(x - (float)hh);
    }
    const int ks = lane >> 3, q = (lane >> 1) & 3, jb = (lane & 1) * 4;
    _Float16* p = e_frag + ((size_t)(nt * 8 + ks)) * 1024 + (q * 16 + l15) * 8 + jb;
    *(half4*)p = h;
    *(half4*)(p + 512) = l;
    #pragma unroll
    for (int m = 32; m >= 1; m >>= 1) ss += __shfl_xor(ss, m, 64);
    if (lane == 0) e_norm[c] = ss;
}

// ---- phase 1: hh-only screen (R7 version, measured 98 us). Tracks per-row
// (min1, idx1, min2); rows with min2-min1 <= T are flagged for exact
// rescore by vq_exact16. T >= 2*E where E = 2*2.001*2^-11*||z||*||e||max
// rigorously bounds |approx - exact| (dropped zh*el + zl*e terms,
// Cauchy-Schwarz), so non-flagged rows provably have the exact argmin.
__global__ __launch_bounds__(256, 2)
void vq_screen(const float* __restrict__ z,
               const _Float16* __restrict__ e_frag,
               const float* __restrict__ e_norm,
               const float* __restrict__ emb,
               float* __restrict__ zq,
               float* __restrict__ idxf,
               int* __restrict__ count,
               int* __restrict__ list) {
    __shared__ _Float16 sA[32 * 512];         // hi only: [mt*8+ks][512] = 32 KB
    __shared__ float    s_nrm[N_CODES];       // 4 KB
    __shared__ float    s_znrm[BM];
    __shared__ float    s_red[4];
    __shared__ float4   s_best[BM][5];        // (m1, idx, m2, -) per wave slot
    __shared__ int      s_idx[BM];

    const int t = threadIdx.x;
    const int w = t >> 6, lane = t & 63, quad = lane >> 4, l15 = lane & 15;
    const int rowblk = blockIdx.x * BM;

    float n0 = e_norm[t], n1 = e_norm[t + 256], n2 = e_norm[t + 512], n3 = e_norm[t + 768];
    s_nrm[t] = n0; s_nrm[t + 256] = n1; s_nrm[t + 512] = n2; s_nrm[t + 768] = n3;
    float mx = fmaxf(fmaxf(n0, n1), fmaxf(n2, n3));
    #pragma unroll
    for (int m = 1; m < 64; m <<= 1) mx = fmaxf(mx, __shfl_xor(mx, m, 64));
    if (lane == 0) s_red[w] = mx;

    // ---- stage A (hi only) + per-row ||z||^2; conflict-free LDS writes.
    float ss = 0.f;
    #pragma unroll
    for (int i = 0; i < 8; ++i) {
        const int row = w * 16 + l15;
        const int col = i * 32 + quad * 8;
        float8v v = *(const float8v*)(z + (size_t)(rowblk + row) * DIM + col);
        half8 h;
        #pragma unroll
        for (int j = 0; j < 8; ++j) {
            float x = v[j];
            ss += x * x;
            h[j] = (_Float16)x;
        }
        *(half8*)(sA + (size_t)(w * 8 + i) * 512 + lane * 8) = h;
    }
    ss += __shfl_xor(ss, 16, 64);     // sum the 4 quads of the same row
    ss += __shfl_xor(ss, 32, 64);
    if (quad == 0) s_znrm[w * 16 + l15] = ss;
    __syncthreads();   // the only compute barrier

    for (int pass = 0; pass < 2; ++pass) {
        const int ntbase = w * 16 + pass * 8;
        float4v acc[4][8] = {};

        #pragma unroll
        for (int ks = 0; ks < 8; ++ks) {
            half8 bh[8];
            #pragma unroll
            for (int nt = 0; nt < 8; ++nt)
                bh[nt] = *(const half8*)(e_frag + ((size_t)((ntbase + nt) * 8 + ks)) * 1024 + lane * 8);
            __builtin_amdgcn_s_setprio(1);
            #pragma unroll
            for (int mt = 0; mt < 4; ++mt) {
                half8 ah = *(const half8*)(sA + (size_t)(mt * 8 + ks) * 512 + lane * 8);
                #pragma unroll
                for (int nt = 0; nt < 8; ++nt)
                    acc[mt][nt] = __builtin_amdgcn_mfma_f32_16x16x32_f16(ah, bh[nt], acc[mt][nt], 0, 0, 0);
            }
            __builtin_amdgcn_s_setprio(0);
        }

        // ---- epilogue: per-row (min1, idx, min2) over this wave's 128 codes.
        // C/D layout: col = lane&15, row = quad*4 + reg.
        float nrm[8]; int cg[8];
        #pragma unroll
        for (int nt = 0; nt < 8; ++nt) {
            cg[nt]  = (ntbase + nt) * 16 + l15;
            nrm[nt] = s_nrm[cg[nt]];
        }
        #pragma unroll
        for (int mt = 0; mt < 4; ++mt) {
            #pragma unroll
            for (int r = 0; r < 4; ++r) {
                float m1 = nrm[0] - 2.0f * acc[mt][0][r]; int i1 = cg[0];
                float m2 = 1e30f;
                #pragma unroll
                for (int nt = 1; nt < 8; ++nt) {
                    float s = nrm[nt] - 2.0f * acc[mt][nt][r];
                    if (s < m1) { m2 = m1; m1 = s; i1 = cg[nt]; }  // ascending: strict <
                    else m2 = fminf(m2, s);
                }
                #pragma unroll
                for (int m = 1; m < 16; m <<= 1) {   // merge 16 l15 lanes (same row)
                    float o1 = __shfl_xor(m1, m, 64);
                    int   oi = __shfl_xor(i1, m, 64);
                    float o2 = __shfl_xor(m2, m, 64);
                    if (o1 < m1 || (o1 == m1 && oi < i1)) {
                        m2 = fminf(m1, o2); m1 = o1; i1 = oi;
                    } else {
                        m2 = fminf(m2, o1);
                    }
                }
                if (l15 == 0) {
                    const int row = mt * 16 + quad * 4 + r;
                    if (pass == 0) {
                        float4 pr; pr.x = m1; pr.y = (float)i1; pr.z = m2; pr.w = 0.f;
                        s_best[row][w] = pr;
                    } else {
                        // merge with pass-0 (lower codes stored first: ties keep stored)
                        float4 pv = s_best[row][w];
                        float4 pr;
                        if (m1 < pv.x) { pr.x = m1; pr.y = (float)i1; pr.z = fminf(pv.x, m2); }
                        else           { pr.x = pv.x; pr.y = pv.y;     pr.z = fminf(pv.z, m1); }
                        pr.w = 0.f;
                        s_best[row][w] = pr;
                    }
                }
            }
        }
    }
    __syncthreads();

    // ---- block reduce over 4 wave slots/row; write idx; flag tight rows
    if (t < BM) {
        float4 b0 = s_best[t][0];
        float m1 = b0.x, fi = b0.y, m2 = b0.z;
        #pragma unroll
        for (int s = 1; s < 4; ++s) {     // slots in ascending-code order
            float4 bv = s_best[t][s];
            if (bv.x < m1 || (bv.x == m1 && bv.y < fi)) {
                m2 = fminf(m1, bv.z); m1 = bv.x; fi = bv.y;
            } else {
                m2 = fminf(m2, bv.x);
            }
        }
        s_idx[t] = (int)fi;
        idxf[rowblk + t] = fi;
        float emax = sqrtf(fmaxf(fmaxf(s_red[0], s_red[1]), fmaxf(s_red[2], s_red[3])));
        float T = 0.005f * sqrtf(s_znrm[t]) * emax + 0.05f;   // >= 2*error bound
        if (m2 - m1 <= T) {
            int pos = atomicAdd(count, 1);
            list[pos] = rowblk + t;
        }
    }
    __syncthreads();

    // ---- fused gather: 4 threads/row, 16 float4 each
    const float4v* emb4 = (const float4v*)emb;
    float4v* zq4 = (float4v*)zq;
    const int rr = t >> 2, cb = t & 3;
    const int code = s_idx[rr];
    #pragma unroll
    for (int i = 0; i < 16; ++i) {
        const int chunk = cb + i * 4;
        zq4[(size_t)(rowblk + rr) * 64 + chunk] = emb4[(size_t)code * 64 + chunk];
    }
}

// ---- backstop: exact hi/lo 3-sweep for flagged rows. BM2=16 rows/block,
// grid-stride; wave w covers codes w*256..+255 in 2 passes of 8 nt
// (acc[8] = 32 AGPR). Small blocks -> low per-block latency, ~450 blocks
// at the measured ~11% flag rate -> ~2 blocks/CU.
__global__ __launch_bounds__(256, 2)
void vq_exact16(const float* __restrict__ z,
                const _Float16* __restrict__ e_frag,
                const float* __restrict__ e_norm,
                const float* __restrict__ emb,
                float* __restrict__ zq,
                float* __restrict__ idxf,
                const int* __restrict__ count,
                const int* __restrict__ list) {
    const int cnt = *count;

    __shared__ _Float16 sA[8 * 2 * 512];      // [ks][hi|lo][512] = 16 KB
    __shared__ float    s_nrm[N_CODES];
    __shared__ float2   s_best[BM2][5];
    __shared__ int      s_idx[BM2], s_rows[BM2];

    const int t = threadIdx.x;
    const int w = t >> 6, lane = t & 63, quad = lane >> 4, l15 = lane & 15;

    if (blockIdx.x * BM2 >= cnt) return;

    s_nrm[t]       = e_norm[t];
    s_nrm[t + 256] = e_norm[t + 256];
    s_nrm[t + 512] = e_norm[t + 512];
    s_nrm[t + 768] = e_norm[t + 768];

    for (int base = blockIdx.x * BM2; base < cnt; base += gridDim.x * BM2) {
        __syncthreads();                       // protect sA/s_rows reuse
        if (t < BM2) {
            int slot = base + t;
            s_rows[t] = list[slot < cnt ? slot : cnt - 1];
        }
        __syncthreads();

        // stage 16 rows, hi/lo: wave w does ks = w and w+4
        #pragma unroll
        for (int i = 0; i < 2; ++i) {
            const int ks = w + i * 4;
            const int grow = s_rows[l15];
            const int col = ks * 32 + quad * 8;
            float8v v = *(const float8v*)(z + (size_t)grow * DIM + col);
            half8 h, lo;
            #pragma unroll
            for (int j = 0; j < 8; ++j) {
                float x = v[j];
                _Float16 hh = (_Float16)x;
                h[j] = hh;
                lo[j] = (_Float16)(x - (float)hh);
            }
            _Float16* p = sA + (size_t)(ks * 2) * 512 + lane * 8;
            *(half8*)p = h;
            *(half8*)(p + 512) = lo;
        }
        __syncthreads();

        for (int pass = 0; pass < 2; ++pass) {
            const int ntbase = w * 16 + pass * 8;
            float4v acc[8] = {};

            #pragma unroll
            for (int ks = 0; ks < 8; ++ks) {
                half8 bh[8], bl[8];
                #pragma unroll
                for (int nt = 0; nt < 8; ++nt) {
                    const _Float16* bp = e_frag + ((size_t)((ntbase + nt) * 8 + ks)) * 1024 + lane * 8;
                    bh[nt] = *(const half8*)bp;
                    bl[nt] = *(const half8*)(bp + 512);
                }
                const _Float16* ap = sA + (size_t)(ks * 2) * 512 + lane * 8;
                half8 ah = *(const half8*)ap;
                half8 al = *(const half8*)(ap + 512);
                __builtin_amdgcn_s_setprio(1);
                #pragma unroll
                for (int nt = 0; nt < 8; ++nt)
                    acc[nt] = __builtin_amdgcn_mfma_f32_16x16x32_f16(ah, bh[nt], acc[nt], 0, 0, 0);
                #pragma unroll
                for (int nt = 0; nt < 8; ++nt)
                    acc[nt] = __builtin_amdgcn_mfma_f32_16x16x32_f16(ah, bl[nt], acc[nt], 0, 0, 0);
                #pragma unroll
                for (int nt = 0; nt < 8; ++nt)
                    acc[nt] = __builtin_amdgcn_mfma_f32_16x16x32_f16(al, bh[nt], acc[nt], 0, 0, 0);
                __builtin_amdgcn_s_setprio(0);
            }

            float nrm[8]; int cg[8];
            #pragma unroll
            for (int nt = 0; nt < 8; ++nt) {
                cg[nt]  = (ntbase + nt) * 16 + l15;
                nrm[nt] = s_nrm[cg[nt]];
            }
            #pragma unroll
            for (int r = 0; r < 4; ++r) {
                float bs = nrm[0] - 2.0f * acc[0][r]; int bi = cg[0];
                #pragma unroll
                for (int nt = 1; nt < 8; ++nt) {
                    float s = nrm[nt] - 2.0f * acc[nt][r];
                    if (s < bs) { bs = s; bi = cg[nt]; }
                }
                #pragma unroll
                for (int m = 1; m < 16; m <<= 1) {
                    float s2 = __shfl_xor(bs, m, 64);
                    int   i2 = __shfl_xor(bi, m, 64);
                    if (s2 < bs || (s2 == bs && i2 < bi)) { bs = s2; bi = i2; }
                }
                if (l15 == 0) {
                    const int row = quad * 4 + r;
                    if (pass == 0) {
                        float2 pr; pr.x = bs; pr.y = (float)bi;
                        s_best[row][w] = pr;
                    } else {
                        float2 pv = s_best[row][w];
                        if (bs < pv.x) {
                            float2 pr; pr.x = bs; pr.y = (float)bi;
                            s_best[row][w] = pr;
                        }
                    }
                }
            }
        }
        __syncthreads();

        if (t < BM2) {
            float2 p0 = s_best[t][0];
            float bs = p0.x, bi = p0.y;
            #pragma unroll
            for (int s = 1; s < 4; ++s) {
                float2 pv = s_best[t][s];
                if (pv.x < bs || (pv.x == bs && pv.y < bi)) { bs = pv.x; bi = pv.y; }
            }
            s_idx[t] = (int)bi;
            idxf[s_rows[t]] = bi;
        }
        __syncthreads();

        // gather: 16 threads/row, 4 float4 each
        const float4v* emb4 = (const float4v*)emb;
        float4v* zq4 = (float4v*)zq;
        const int rr = t >> 4, cb = t & 15;
        const int grow = s_rows[rr];
        const int code = s_idx[rr];
        #pragma unroll
        for (int i = 0; i < 4; ++i) {
            const int chunk = cb + i * 16;
            zq4[(size_t)grow * 64 + chunk] = emb4[(size_t)code * 64 + chunk];
        }
    }
}

// ============== fallback path (small workspace): R3 kernel verbatim ======
__global__ __launch_bounds__(256, 2)
void vq_main(const float* __restrict__ z,
             const _Float16* __restrict__ e_frag,
             const float* __restrict__ e_norm,
             const float* __restrict__ emb,
             float* __restrict__ zq,
             float* __restrict__ idxf,
             int fused_gather) {
    __shared__ _Float16 sA[32 * 2 * 512];
    __shared__ float    s_nrm[N_CODES];
    __shared__ float2   s_best[BM][5];
    __shared__ int      s_idx[BM];

    const int t = threadIdx.x;
    const int w = t >> 6, lane = t & 63, quad = lane >> 4, l15 = lane & 15;
    const int rowblk = blockIdx.x * BM;

    s_nrm[t]       = e_norm[t];
    s_nrm[t + 256] = e_norm[t + 256];
    s_nrm[t + 512] = e_norm[t + 512];
    s_nrm[t + 768] = e_norm[t + 768];

    #pragma unroll
    for (int i = 0; i < 8; ++i) {
        const int row = w * 16 + l15;
        const int col = i * 32 + quad * 8;
        float8v v = *(const float8v*)(z + (size_t)(rowblk + row) * DIM + col);
        half8 h, lo;
        #pragma unroll
        for (int j = 0; j < 8; ++j) {
            float x = v[j];
            _Float16 hh = (_Float16)x;
            h[j] = hh;
            lo[j] = (_Float16)(x - (float)hh);
        }
        _Float16* p = sA + (size_t)((w * 8 + i) * 2) * 512 + lane * 8;
        *(half8*)p = h;
        *(half8*)(p + 512) = lo;
    }
    __syncthreads();

    for (int pass = 0; pass < 2; ++pass) {
        const int ntbase = w * 16 + pass * 8;
        float4v acc[4][8] = {};

        #pragma unroll
        for (int ks = 0; ks < 8; ++ks) {
            half8 bh[8], bl[8];
            #pragma unroll
            for (int nt = 0; nt < 8; ++nt) {
                const _Float16* bp = e_frag + ((size_t)((ntbase + nt) * 8 + ks)) * 1024 + lane * 8;
                bh[nt] = *(const half8*)bp;
                bl[nt] = *(const half8*)(bp + 512);
            }
            __builtin_amdgcn_s_setprio(1);
            #pragma unroll
            for (int mt = 0; mt < 4; ++mt) {
                const _Float16* ap = sA + (size_t)((mt * 8 + ks) * 2) * 512 + lane * 8;
                half8 ah = *(const half8*)ap;
                half8 al = *(const half8*)(ap + 512);
                #pragma unroll
                for (int nt = 0; nt < 8; ++nt)
                    acc[mt][nt] = __builtin_amdgcn_mfma_f32_16x16x32_f16(ah, bh[nt], acc[mt][nt], 0, 0, 0);
                #pragma unroll
                for (int nt = 0; nt < 8; ++nt)
                    acc[mt][nt] = __builtin_amdgcn_mfma_f32_16x16x32_f16(ah, bl[nt], acc[mt][nt], 0, 0, 0);
                #pragma unroll
                for (int nt = 0; nt < 8; ++nt)
                    acc[mt][nt] = __builtin_amdgcn_mfma_f32_16x16x32_f16(al, bh[nt], acc[mt][nt], 0, 0, 0);
            }
            __builtin_amdgcn_s_setprio(0);
        }

        float nrm[8]; int cg[8];
        #pragma unroll
        for (int nt = 0; nt < 8; ++nt) {
            cg[nt]  = (ntbase + nt) * 16 + l15;
            nrm[nt] = s_nrm[cg[nt]];
        }
        #pragma unroll
        for (int mt = 0; mt < 4; ++mt) {
            #pragma unroll
            for (int r = 0; r < 4; ++r) {
                float bs = nrm[0] - 2.0f * acc[mt][0][r]; int bi = cg[0];
                #pragma unroll
                for (int nt = 1; nt < 8; ++nt) {
                    float s = nrm[nt] - 2.0f * acc[mt][nt][r];
                    if (s < bs) { bs = s; bi = cg[nt]; }
                }
                #pragma unroll
                for (int m = 1; m < 16; m <<= 1) {
                    float s2 = __shfl_xor(bs, m, 64);
                    int   i2 = __shfl_xor(bi, m, 64);
                    if (s2 < bs || (s2 == bs && i2 < bi)) { bs = s2; bi = i2; }
                }
                if (l15 == 0) {
                    const int row = mt * 16 + quad * 4 + r;
                    if (pass == 0) {
                        float2 pr; pr.x = bs; pr.y = (float)bi;
                        s_best[row][w] = pr;
                    } else {
                        float2 pv = s_best[row][w];
                        if (bs < pv.x) {
                            float2 pr; pr.x = bs; pr.y = (float)bi;
                            s_best[row][w] = pr;
                        }
                    }
                }
            }
        }
    }
    __syncthreads();

    if (t < BM) {
        float2 p0 = s_best[t][0];
        float bs = p0.x, bi = p0.y;
        #pragma unroll
        for (int s = 1; s < 4; ++s) {
            float2 pv = s_best[t][s];
            if (pv.x < bs || (pv.x == bs && pv.y < bi)) { bs = pv.x; bi = pv.y; }
        }
        s_idx[t] = (int)bi;
        idxf[rowblk + t] = bi;
    }

    if (!fused_gather) return;
    __syncthreads();

    const float4v* emb4 = (const float4v*)emb;
    float4v* zq4 = (float4v*)zq;
    const int rr = t >> 2, cb = t & 3;
    const int code = s_idx[rr];
    #pragma unroll
    for (int i = 0; i < 16; ++i) {
        const int chunk = cb + i * 4;
        zq4[(size_t)(rowblk + rr) * 64 + chunk] = emb4[(size_t)code * 64 + chunk];
    }
}

__global__ __launch_bounds__(256)
void vq_gather(const float* __restrict__ emb,
               const float* __restrict__ idxf,
               float* __restrict__ zq) {
    const int tid  = blockIdx.x * 256 + threadIdx.x;
    const int r    = tid >> 6;
    const int lane = tid & 63;
    const int idx  = (int)idxf[r];
    const float4* ep = (const float4*)(emb + (size_t)idx * DIM);
    ((float4*)(zq + (size_t)r * DIM))[lane] = ep[lane];
}

extern "C" void kernel_launch(void* const* d_in, const int* in_sizes, int n_in,
                              void* d_out, int out_size, void* d_ws, size_t ws_size,
                              hipStream_t stream) {
    const float* z   = (const float*)d_in[0];   // (64,32,32,256) fp32
    const float* emb = (const float*)d_in[1];   // (1024,256) fp32

    float* zq   = (float*)d_out;                        // output 0
    float* idxf = zq + (size_t)N_ROWS * DIM;            // output 1

    const size_t efrag_sz = (size_t)N_CODES * DIM * 2 * sizeof(_Float16); // 1 MB
    const size_t list_sz  = (size_t)N_ROWS * sizeof(int);                 // 256 KB
    const size_t need_p   = 4096 + efrag_sz + 4096 + list_sz;

    if (ws_size >= need_p) {
        // screen + BM2=16 exact backstop
        float*    e_norm = (float*)d_ws;
        _Float16* e_frag = (_Float16*)((char*)d_ws + 4096);
        int*      count  = (int*)((char*)d_ws + 4096 + efrag_sz);
        int*      list   = (int*)((char*)d_ws + 4096 + efrag_sz + 4096);
        vq_prep<<<N_CODES, 64, 0, stream>>>(emb, e_norm, e_frag, count);
        vq_screen<<<NBLKS, 256, 0, stream>>>(z, e_frag, e_norm, emb, zq, idxf, count, list);
        vq_exact16<<<512, 256, 0, stream>>>(z, e_frag, e_norm, emb, zq, idxf, count, list);
    } else {
        // fallback: measured-best R3 path
        const size_t need = 4096 + efrag_sz;
        const int in_ws = (ws_size >= need);
        char* base = in_ws ? (char*)d_ws : (char*)d_out;
        float*    e_norm = (float*)base;
        _Float16* e_frag = (_Float16*)(base + 4096);
        vq_prep<<<N_CODES, 64, 0, stream>>>(emb, e_norm, e_frag, (int*)0);
        vq_main<<<NBLKS, 256, 0, stream>>>(z, e_frag, e_norm, emb, zq, idxf, in_ws);
        if (!in_ws)
            vq_gather<<<(N_ROWS * 64) / 256, 256, 0, stream>>>(emb, idxf, zq);
    }
}

// Round 10
// 198.958 us; speedup vs baseline: 2.9412x; 2.9412x over previous
//
#include <hip/hip_runtime.h>

typedef _Float16 half8  __attribute__((ext_vector_type(8)));
typedef _Float16 half4  __attribute__((ext_vector_type(4)));
typedef float    float4v __attribute__((ext_vector_type(4)));
typedef float    float8v __attribute__((ext_vector_type(8)));

#define N_ROWS  65536   // 64*32*32
#define N_CODES 1024
#define DIM     256
#define BM      64      // rows per block (screen / fallback / backstop rowgroup)
#define NBLKS   (N_ROWS / BM)   // 1024

// pack (score, code) into a sortable u64: flipped-float bits high, code low.
// min() = lowest score, then lowest code — exactly reference argmin semantics.
__device__ __forceinline__ unsigned long long packScore(float s, int code) {
    unsigned u = __float_as_uint(s);
    u ^= (u >> 31) ? 0xFFFFFFFFu : 0x80000000u;
    return ((unsigned long long)u << 32) | (unsigned)code;
}

// ---- prep: one wave per code. ||e||^2, ||e_lo||^2, hi/lo f16 split in MFMA
// B-fragment order (16x16x32): frag block b = nt*8 + ks holds 1024 halves:
// [hi 512][lo 512], chunk p = quad*16 + l15 -> code = nt*16+l15,
// k = ks*32 + quad*8 + j.  Also resets the backstop counter.
__global__ __launch_bounds__(64)
void vq_prep(const float* __restrict__ emb, float* __restrict__ e_norm,
             float* __restrict__ el2, _Float16* __restrict__ e_frag,
             int* __restrict__ count) {
    const int c = blockIdx.x, lane = threadIdx.x;
    const int l15 = c & 15, nt = c >> 4;
    if (count && c == 0 && lane == 0) *count = 0;
    float4v v = ((const float4v*)(emb + (size_t)c * DIM))[lane];
    half4 h, l;
    float ss = 0.f, ssl = 0.f;
    #pragma unroll
    for (int j = 0; j < 4; ++j) {
        float x = v[j];
        ss += x * x;
        _Float16 hh = (_Float16)x;
        float xl = x - (float)hh;
        ssl += xl * xl;
        h[j] = hh;
        l[j] = (_Float16)xl;
    }
    const int ks = lane >> 3, q = (lane >> 1) & 3, jb = (lane & 1) * 4;
    _Float16* p = e_frag + ((size_t)(nt * 8 + ks)) * 1024 + (q * 16 + l15) * 8 + jb;
    *(half4*)p = h;
    *(half4*)(p + 512) = l;
    #pragma unroll
    for (int m = 32; m >= 1; m >>= 1) {
        ss  += __shfl_xor(ss, m, 64);
        ssl += __shfl_xor(ssl, m, 64);
    }
    if (lane == 0) {
        e_norm[c] = ss;
        if (el2) el2[c] = ssl;
    }
}

// ---- phase 1: hh-only screen (R7 structure, measured 98 us) + tightened
// rigorous T. Tracks per-row (min1, idx1, min2); rows with min2-min1 <= T
// flagged for exact rescore. |approx-exact| <= E = ||z_lo||*max||e|| +
// ||z_hi||*max||e_lo|| (Cauchy-Schwarz on the two dropped product terms);
// T = 2E + 0.02 slack (fp32 MFMA accumulation) => non-flagged rows provably
// have the exact argmin. Norms measured, not worst-case: ~4x tighter than
// the 2^-11 bound -> flag rate ~2.5%.
__global__ __launch_bounds__(256, 2)
void vq_screen(const float* __restrict__ z,
               const _Float16* __restrict__ e_frag,
               const float* __restrict__ e_norm,
               const float* __restrict__ el2,
               const float* __restrict__ emb,
               float* __restrict__ zq,
               float* __restrict__ idxf,
               int* __restrict__ count,
               int* __restrict__ list,
               unsigned long long* __restrict__ packed) {
    __shared__ _Float16 sA[32 * 512];         // hi only: [mt*8+ks][512] = 32 KB
    __shared__ float    s_nrm[N_CODES];       // 4 KB
    __shared__ float    s_znrm[BM];
    __shared__ float    s_zlnrm[BM];
    __shared__ float    s_red[4], s_redl[4];
    __shared__ float4   s_best[BM][5];        // (m1, idx, m2, -) per wave slot
    __shared__ int      s_idx[BM];

    const int t = threadIdx.x;
    const int w = t >> 6, lane = t & 63, quad = lane >> 4, l15 = lane & 15;
    const int rowblk = blockIdx.x * BM;

    float n0 = e_norm[t], n1 = e_norm[t + 256], n2 = e_norm[t + 512], n3 = e_norm[t + 768];
    s_nrm[t] = n0; s_nrm[t + 256] = n1; s_nrm[t + 512] = n2; s_nrm[t + 768] = n3;
    float mx = fmaxf(fmaxf(n0, n1), fmaxf(n2, n3));
    float q0 = el2[t], q1 = el2[t + 256], q2 = el2[t + 512], q3 = el2[t + 768];
    float mxl = fmaxf(fmaxf(q0, q1), fmaxf(q2, q3));
    #pragma unroll
    for (int m = 1; m < 64; m <<= 1) {
        mx  = fmaxf(mx,  __shfl_xor(mx, m, 64));
        mxl = fmaxf(mxl, __shfl_xor(mxl, m, 64));
    }
    if (lane == 0) { s_red[w] = mx; s_redl[w] = mxl; }

    // ---- stage A (hi only) + per-row ||z||^2, ||z_lo||^2; conflict-free.
    float ss = 0.f, ssl = 0.f;
    #pragma unroll
    for (int i = 0; i < 8; ++i) {
        const int row = w * 16 + l15;
        const int col = i * 32 + quad * 8;
        float8v v = *(const float8v*)(z + (size_t)(rowblk + row) * DIM + col);
        half8 h;
        #pragma unroll
        for (int j = 0; j < 8; ++j) {
            float x = v[j];
            ss += x * x;
            _Float16 hh = (_Float16)x;
            float xl = x - (float)hh;
            ssl += xl * xl;
            h[j] = hh;
        }
        *(half8*)(sA + (size_t)(w * 8 + i) * 512 + lane * 8) = h;
    }
    ss  += __shfl_xor(ss, 16, 64);     // sum the 4 quads of the same row
    ss  += __shfl_xor(ss, 32, 64);
    ssl += __shfl_xor(ssl, 16, 64);
    ssl += __shfl_xor(ssl, 32, 64);
    if (quad == 0) { s_znrm[w * 16 + l15] = ss; s_zlnrm[w * 16 + l15] = ssl; }
    __syncthreads();   // the only compute barrier

    for (int pass = 0; pass < 2; ++pass) {
        const int ntbase = w * 16 + pass * 8;
        float4v acc[4][8] = {};

        #pragma unroll
        for (int ks = 0; ks < 8; ++ks) {
            half8 bh[8];
            #pragma unroll
            for (int nt = 0; nt < 8; ++nt)
                bh[nt] = *(const half8*)(e_frag + ((size_t)((ntbase + nt) * 8 + ks)) * 1024 + lane * 8);
            __builtin_amdgcn_s_setprio(1);
            #pragma unroll
            for (int mt = 0; mt < 4; ++mt) {
                half8 ah = *(const half8*)(sA + (size_t)(mt * 8 + ks) * 512 + lane * 8);
                #pragma unroll
                for (int nt = 0; nt < 8; ++nt)
                    acc[mt][nt] = __builtin_amdgcn_mfma_f32_16x16x32_f16(ah, bh[nt], acc[mt][nt], 0, 0, 0);
            }
            __builtin_amdgcn_s_setprio(0);
        }

        // ---- epilogue: per-row (min1, idx, min2) over this wave's 128 codes.
        // C/D layout: col = lane&15, row = quad*4 + reg.
        float nrm[8]; int cg[8];
        #pragma unroll
        for (int nt = 0; nt < 8; ++nt) {
            cg[nt]  = (ntbase + nt) * 16 + l15;
            nrm[nt] = s_nrm[cg[nt]];
        }
        #pragma unroll
        for (int mt = 0; mt < 4; ++mt) {
            #pragma unroll
            for (int r = 0; r < 4; ++r) {
                float m1 = nrm[0] - 2.0f * acc[mt][0][r]; int i1 = cg[0];
                float m2 = 1e30f;
                #pragma unroll
                for (int nt = 1; nt < 8; ++nt) {
                    float s = nrm[nt] - 2.0f * acc[mt][nt][r];
                    if (s < m1) { m2 = m1; m1 = s; i1 = cg[nt]; }  // ascending: strict <
                    else m2 = fminf(m2, s);
                }
                #pragma unroll
                for (int m = 1; m < 16; m <<= 1) {   // merge 16 l15 lanes (same row)
                    float o1 = __shfl_xor(m1, m, 64);
                    int   oi = __shfl_xor(i1, m, 64);
                    float o2 = __shfl_xor(m2, m, 64);
                    if (o1 < m1 || (o1 == m1 && oi < i1)) {
                        m2 = fminf(m1, o2); m1 = o1; i1 = oi;
                    } else {
                        m2 = fminf(m2, o1);
                    }
                }
                if (l15 == 0) {
                    const int row = mt * 16 + quad * 4 + r;
                    if (pass == 0) {
                        float4 pr; pr.x = m1; pr.y = (float)i1; pr.z = m2; pr.w = 0.f;
                        s_best[row][w] = pr;
                    } else {
                        // merge with pass-0 (lower codes stored first: ties keep stored)
                        float4 pv = s_best[row][w];
                        float4 pr;
                        if (m1 < pv.x) { pr.x = m1; pr.y = (float)i1; pr.z = fminf(pv.x, m2); }
                        else           { pr.x = pv.x; pr.y = pv.y;     pr.z = fminf(pv.z, m1); }
                        pr.w = 0.f;
                        s_best[row][w] = pr;
                    }
                }
            }
        }
    }
    __syncthreads();

    // ---- block reduce over 4 wave slots/row; write idx; flag tight rows
    if (t < BM) {
        float4 b0 = s_best[t][0];
        float m1 = b0.x, fi = b0.y, m2 = b0.z;
        #pragma unroll
        for (int s = 1; s < 4; ++s) {     // slots in ascending-code order
            float4 bv = s_best[t][s];
            if (bv.x < m1 || (bv.x == m1 && bv.y < fi)) {
                m2 = fminf(m1, bv.z); m1 = bv.x; fi = bv.y;
            } else {
                m2 = fminf(m2, bv.x);
            }
        }
        s_idx[t] = (int)fi;
        idxf[rowblk + t] = fi;
        float emax  = sqrtf(fmaxf(fmaxf(s_red[0],  s_red[1]),  fmaxf(s_red[2],  s_red[3])));
        float elmax = sqrtf(fmaxf(fmaxf(s_redl[0], s_redl[1]), fmaxf(s_redl[2], s_redl[3])));
        // rigorous: |approx-exact| <= ||z_lo||*emax + ||z_hi||*elmax,
        // ||z_hi|| <= 1.001*||z||; + 0.02 fp32-accum slack.
        float T = 2.0f * (sqrtf(s_zlnrm[t]) * emax + 1.001f * sqrtf(s_znrm[t]) * elmax) + 0.02f;
        if (m2 - m1 <= T) {
            int pos = atomicAdd(count, 1);
            list[pos] = rowblk + t;
            packed[rowblk + t] = 0xFFFFFFFFFFFFFFFFull;   // init for atomicMin
        }
    }
    __syncthreads();

    // ---- fused gather: 4 threads/row, 16 float4 each
    const float4v* emb4 = (const float4v*)emb;
    float4v* zq4 = (float4v*)zq;
    const int rr = t >> 2, cb = t & 3;
    const int code = s_idx[rr];
    #pragma unroll
    for (int i = 0; i < 16; ++i) {
        const int chunk = cb + i * 4;
        zq4[(size_t)(rowblk + rr) * 64 + chunk] = emb4[(size_t)code * 64 + chunk];
    }
}

// ---- backstop: exact hi/lo 3-sweep for flagged rows, CODE-SPLIT 8-WAY so
// per-block serial latency is ~1/8 of a full rescore. Block b: rowgroup
// g = b>>3 (64 rows from list), code-oct = b&7 (128 codes). acc[4][2]=32
// regs, B regs transient 32 -> no spill (R9's exact16 spilled at 190 regs).
// Cross-block merge via atomicMin on packed u64 (deterministic scores ->
// order-independent).
__global__ __launch_bounds__(256, 2)
void vq_resc(const float* __restrict__ z,
             const _Float16* __restrict__ e_frag,
             const float* __restrict__ e_norm,
             const int* __restrict__ count,
             const int* __restrict__ list,
             unsigned long long* __restrict__ packed) {
    const int cnt = *count;
    const int g = blockIdx.x >> 3, oct = blockIdx.x & 7;
    if (g * BM >= cnt) return;

    __shared__ _Float16 sA[32 * 2 * 512];     // [mt*8+ks][hi|lo][512] = 64 KB
    __shared__ float2   s_best[BM][5];
    __shared__ int      s_rows[BM];

    const int t = threadIdx.x;
    const int w = t >> 6, lane = t & 63, quad = lane >> 4, l15 = lane & 15;

    if (t < BM) {
        int slot = g * BM + t;
        s_rows[t] = list[slot < cnt ? slot : cnt - 1];
    }
    __syncthreads();

    // stage 64 rows (indirect), hi/lo, full K — same layout as R3 main
    #pragma unroll
    for (int i = 0; i < 8; ++i) {
        const int row = w * 16 + l15;
        const int grow = s_rows[row];
        const int col = i * 32 + quad * 8;
        float8v v = *(const float8v*)(z + (size_t)grow * DIM + col);
        half8 h, lo;
        #pragma unroll
        for (int j = 0; j < 8; ++j) {
            float x = v[j];
            _Float16 hh = (_Float16)x;
            h[j] = hh;
            lo[j] = (_Float16)(x - (float)hh);
        }
        _Float16* p = sA + (size_t)((w * 8 + i) * 2) * 512 + lane * 8;
        *(half8*)p = h;
        *(half8*)(p + 512) = lo;
    }
    __syncthreads();

    // this block's codes: oct*128 .. +127; wave w gets nt-tiles ntbase..+1
    const int ntbase = oct * 8 + w * 2;
    float4v acc[4][2] = {};

    #pragma unroll
    for (int ks = 0; ks < 8; ++ks) {
        half8 bh[2], bl[2];
        #pragma unroll
        for (int nt = 0; nt < 2; ++nt) {
            const _Float16* bp = e_frag + ((size_t)((ntbase + nt) * 8 + ks)) * 1024 + lane * 8;
            bh[nt] = *(const half8*)bp;
            bl[nt] = *(const half8*)(bp + 512);
        }
        __builtin_amdgcn_s_setprio(1);
        #pragma unroll
        for (int mt = 0; mt < 4; ++mt) {
            const _Float16* ap = sA + (size_t)((mt * 8 + ks) * 2) * 512 + lane * 8;
            half8 ah = *(const half8*)ap;
            half8 al = *(const half8*)(ap + 512);
            #pragma unroll
            for (int nt = 0; nt < 2; ++nt)
                acc[mt][nt] = __builtin_amdgcn_mfma_f32_16x16x32_f16(ah, bh[nt], acc[mt][nt], 0, 0, 0);
            #pragma unroll
            for (int nt = 0; nt < 2; ++nt)
                acc[mt][nt] = __builtin_amdgcn_mfma_f32_16x16x32_f16(ah, bl[nt], acc[mt][nt], 0, 0, 0);
            #pragma unroll
            for (int nt = 0; nt < 2; ++nt)
                acc[mt][nt] = __builtin_amdgcn_mfma_f32_16x16x32_f16(al, bh[nt], acc[mt][nt], 0, 0, 0);
        }
        __builtin_amdgcn_s_setprio(0);
    }

    // epilogue: per-row argmin over this wave's 32 codes -> s_best merge
    float nrm[2]; int cg[2];
    #pragma unroll
    for (int nt = 0; nt < 2; ++nt) {
        cg[nt]  = (ntbase + nt) * 16 + l15;
        nrm[nt] = e_norm[cg[nt]];
    }
    #pragma unroll
    for (int mt = 0; mt < 4; ++mt) {
        #pragma unroll
        for (int r = 0; r < 4; ++r) {
            float bs = nrm[0] - 2.0f * acc[mt][0][r]; int bi = cg[0];
            float s1 = nrm[1] - 2.0f * acc[mt][1][r];
            if (s1 < bs) { bs = s1; bi = cg[1]; }   // ascending: strict <
            #pragma unroll
            for (int m = 1; m < 16; m <<= 1) {
                float s2 = __shfl_xor(bs, m, 64);
                int   i2 = __shfl_xor(bi, m, 64);
                if (s2 < bs || (s2 == bs && i2 < bi)) { bs = s2; bi = i2; }
            }
            if (l15 == 0) {
                float2 pr; pr.x = bs; pr.y = (float)bi;
                s_best[mt * 16 + quad * 4 + r][w] = pr;
            }
        }
    }
    __syncthreads();

    // block reduce (wave slots in ascending-code order) -> one atomicMin/row
    if (t < BM) {
        float2 p0 = s_best[t][0];
        float bs = p0.x, bi = p0.y;
        #pragma unroll
        for (int s = 1; s < 4; ++s) {
            float2 pv = s_best[t][s];
            if (pv.x < bs || (pv.x == bs && pv.y < bi)) { bs = pv.x; bi = pv.y; }
        }
        atomicMin(&packed[s_rows[t]], packScore(bs, (int)bi));
    }
}

// ---- fixer: for flagged rows, read the winning code from packed, rewrite
// idxf and the zq row. Padded slots duplicate the last row (benign dup write).
__global__ __launch_bounds__(256)
void vq_fix(const float* __restrict__ emb,
            const int* __restrict__ count,
            const int* __restrict__ list,
            const unsigned long long* __restrict__ packed,
            float* __restrict__ zq,
            float* __restrict__ idxf) {
    const int cnt = *count;
    const int base = blockIdx.x * BM;
    if (base >= cnt) return;

    __shared__ int s_rows[BM], s_code[BM];
    const int t = threadIdx.x;
    if (t < BM) {
        int slot = base + t;
        int row = list[slot < cnt ? slot : cnt - 1];
        s_rows[t] = row;
        int code = (int)(unsigned)packed[row];
        s_code[t] = code;
        idxf[row] = (float)code;
    }
    __syncthreads();

    const float4v* emb4 = (const float4v*)emb;
    float4v* zq4 = (float4v*)zq;
    const int rr = t >> 2, cb = t & 3;
    const int grow = s_rows[rr];
    const int code = s_code[rr];
    #pragma unroll
    for (int i = 0; i < 16; ++i) {
        const int chunk = cb + i * 4;
        zq4[(size_t)grow * 64 + chunk] = emb4[(size_t)code * 64 + chunk];
    }
}

// ============== fallback path (small workspace): R3 kernel verbatim ======
__global__ __launch_bounds__(256, 2)
void vq_main(const float* __restrict__ z,
             const _Float16* __restrict__ e_frag,
             const float* __restrict__ e_norm,
             const float* __restrict__ emb,
             float* __restrict__ zq,
             float* __restrict__ idxf,
             int fused_gather) {
    __shared__ _Float16 sA[32 * 2 * 512];
    __shared__ float    s_nrm[N_CODES];
    __shared__ float2   s_best[BM][5];
    __shared__ int      s_idx[BM];

    const int t = threadIdx.x;
    const int w = t >> 6, lane = t & 63, quad = lane >> 4, l15 = lane & 15;
    const int rowblk = blockIdx.x * BM;

    s_nrm[t]       = e_norm[t];
    s_nrm[t + 256] = e_norm[t + 256];
    s_nrm[t + 512] = e_norm[t + 512];
    s_nrm[t + 768] = e_norm[t + 768];

    #pragma unroll
    for (int i = 0; i < 8; ++i) {
        const int row = w * 16 + l15;
        const int col = i * 32 + quad * 8;
        float8v v = *(const float8v*)(z + (size_t)(rowblk + row) * DIM + col);
        half8 h, lo;
        #pragma unroll
        for (int j = 0; j < 8; ++j) {
            float x = v[j];
            _Float16 hh = (_Float16)x;
            h[j] = hh;
            lo[j] = (_Float16)(x - (float)hh);
        }
        _Float16* p = sA + (size_t)((w * 8 + i) * 2) * 512 + lane * 8;
        *(half8*)p = h;
        *(half8*)(p + 512) = lo;
    }
    __syncthreads();

    for (int pass = 0; pass < 2; ++pass) {
        const int ntbase = w * 16 + pass * 8;
        float4v acc[4][8] = {};

        #pragma unroll
        for (int ks = 0; ks < 8; ++ks) {
            half8 bh[8], bl[8];
            #pragma unroll
            for (int nt = 0; nt < 8; ++nt) {
                const _Float16* bp = e_frag + ((size_t)((ntbase + nt) * 8 + ks)) * 1024 + lane * 8;
                bh[nt] = *(const half8*)bp;
                bl[nt] = *(const half8*)(bp + 512);
            }
            __builtin_amdgcn_s_setprio(1);
            #pragma unroll
            for (int mt = 0; mt < 4; ++mt) {
                const _Float16* ap = sA + (size_t)((mt * 8 + ks) * 2) * 512 + lane * 8;
                half8 ah = *(const half8*)ap;
                half8 al = *(const half8*)(ap + 512);
                #pragma unroll
                for (int nt = 0; nt < 8; ++nt)
                    acc[mt][nt] = __builtin_amdgcn_mfma_f32_16x16x32_f16(ah, bh[nt], acc[mt][nt], 0, 0, 0);
                #pragma unroll
                for (int nt = 0; nt < 8; ++nt)
                    acc[mt][nt] = __builtin_amdgcn_mfma_f32_16x16x32_f16(ah, bl[nt], acc[mt][nt], 0, 0, 0);
                #pragma unroll
                for (int nt = 0; nt < 8; ++nt)
                    acc[mt][nt] = __builtin_amdgcn_mfma_f32_16x16x32_f16(al, bh[nt], acc[mt][nt], 0, 0, 0);
            }
            __builtin_amdgcn_s_setprio(0);
        }

        float nrm[8]; int cg[8];
        #pragma unroll
        for (int nt = 0; nt < 8; ++nt) {
            cg[nt]  = (ntbase + nt) * 16 + l15;
            nrm[nt] = s_nrm[cg[nt]];
        }
        #pragma unroll
        for (int mt = 0; mt < 4; ++mt) {
            #pragma unroll
            for (int r = 0; r < 4; ++r) {
                float bs = nrm[0] - 2.0f * acc[mt][0][r]; int bi = cg[0];
                #pragma unroll
                for (int nt = 1; nt < 8; ++nt) {
                    float s = nrm[nt] - 2.0f * acc[mt][nt][r];
                    if (s < bs) { bs = s; bi = cg[nt]; }
                }
                #pragma unroll
                for (int m = 1; m < 16; m <<= 1) {
                    float s2 = __shfl_xor(bs, m, 64);
                    int   i2 = __shfl_xor(bi, m, 64);
                    if (s2 < bs || (s2 == bs && i2 < bi)) { bs = s2; bi = i2; }
                }
                if (l15 == 0) {
                    const int row = mt * 16 + quad * 4 + r;
                    if (pass == 0) {
                        float2 pr; pr.x = bs; pr.y = (float)bi;
                        s_best[row][w] = pr;
                    } else {
                        float2 pv = s_best[row][w];
                        if (bs < pv.x) {
                            float2 pr; pr.x = bs; pr.y = (float)bi;
                            s_best[row][w] = pr;
                        }
                    }
                }
            }
        }
    }
    __syncthreads();

    if (t < BM) {
        float2 p0 = s_best[t][0];
        float bs = p0.x, bi = p0.y;
        #pragma unroll
        for (int s = 1; s < 4; ++s) {
            float2 pv = s_best[t][s];
            if (pv.x < bs || (pv.x == bs && pv.y < bi)) { bs = pv.x; bi = pv.y; }
        }
        s_idx[t] = (int)bi;
        idxf[rowblk + t] = bi;
    }

    if (!fused_gather) return;
    __syncthreads();

    const float4v* emb4 = (const float4v*)emb;
    float4v* zq4 = (float4v*)zq;
    const int rr = t >> 2, cb = t & 3;
    const int code = s_idx[rr];
    #pragma unroll
    for (int i = 0; i < 16; ++i) {
        const int chunk = cb + i * 4;
        zq4[(size_t)(rowblk + rr) * 64 + chunk] = emb4[(size_t)code * 64 + chunk];
    }
}

__global__ __launch_bounds__(256)
void vq_gather(const float* __restrict__ emb,
               const float* __restrict__ idxf,
               float* __restrict__ zq) {
    const int tid  = blockIdx.x * 256 + threadIdx.x;
    const int r    = tid >> 6;
    const int lane = tid & 63;
    const int idx  = (int)idxf[r];
    const float4* ep = (const float4*)(emb + (size_t)idx * DIM);
    ((float4*)(zq + (size_t)r * DIM))[lane] = ep[lane];
}

extern "C" void kernel_launch(void* const* d_in, const int* in_sizes, int n_in,
                              void* d_out, int out_size, void* d_ws, size_t ws_size,
                              hipStream_t stream) {
    const float* z   = (const float*)d_in[0];   // (64,32,32,256) fp32
    const float* emb = (const float*)d_in[1];   // (1024,256) fp32

    float* zq   = (float*)d_out;                        // output 0
    float* idxf = zq + (size_t)N_ROWS * DIM;            // output 1

    const size_t efrag_sz  = (size_t)N_CODES * DIM * 2 * sizeof(_Float16);          // 1 MB
    const size_t list_sz   = (size_t)N_ROWS * sizeof(int);                          // 256 KB
    const size_t packed_sz = (size_t)N_ROWS * sizeof(unsigned long long);           // 512 KB
    const size_t off_el2    = 4096;
    const size_t off_efrag  = 8192;
    const size_t off_count  = off_efrag + efrag_sz;
    const size_t off_list   = off_count + 4096;
    const size_t off_packed = off_list + list_sz;
    const size_t need_p     = off_packed + packed_sz;

    if (ws_size >= need_p) {
        // screen + code-split exact backstop (atomicMin merge) + fixer
        float*    e_norm = (float*)d_ws;
        float*    el2    = (float*)((char*)d_ws + off_el2);
        _Float16* e_frag = (_Float16*)((char*)d_ws + off_efrag);
        int*      count  = (int*)((char*)d_ws + off_count);
        int*      list   = (int*)((char*)d_ws + off_list);
        unsigned long long* packed = (unsigned long long*)((char*)d_ws + off_packed);
        vq_prep<<<N_CODES, 64, 0, stream>>>(emb, e_norm, el2, e_frag, count);
        vq_screen<<<NBLKS, 256, 0, stream>>>(z, e_frag, e_norm, el2, emb, zq, idxf, count, list, packed);
        vq_resc<<<NBLKS * 8, 256, 0, stream>>>(z, e_frag, e_norm, count, list, packed);
        vq_fix<<<NBLKS, 256, 0, stream>>>(emb, count, list, packed, zq, idxf);
    } else {
        // fallback: measured-best R3 path
        const size_t need = off_efrag + efrag_sz;
        const int in_ws = (ws_size >= need);
        char* base = in_ws ? (char*)d_ws : (char*)d_out;
        float*    e_norm = (float*)base;
        _Float16* e_frag = (_Float16*)(base + off_efrag);
        vq_prep<<<N_CODES, 64, 0, stream>>>(emb, e_norm, (float*)0, e_frag, (int*)0);
        vq_main<<<NBLKS, 256, 0, stream>>>(z, e_frag, e_norm, emb, zq, idxf, in_ws);
        if (!in_ws)
            vq_gather<<<(N_ROWS * 64) / 256, 256, 0, stream>>>(emb, idxf, zq);
    }
}